// Round 13
// baseline (134.852 us; speedup 1.0000x reference)
//
#include <hip/hip_runtime.h>
#include <hip/hip_bf16.h>
#include <cstdint>

#define DEVI __device__ __forceinline__

typedef __bf16 bf16x8 __attribute__((ext_vector_type(8)));
typedef float  f32x4  __attribute__((ext_vector_type(4)));

constexpr int Hdim = 1024;
constexpr int Vdim = 32000;
constexpr int Ldim = 512;
constexpr int Bdim = 256;

DEVI unsigned short f2bf(float f) {
  __bf16 h = (__bf16)f;                       // RNE
  return __builtin_bit_cast(unsigned short, h);
}

// ===========================================================================
// gemm_flat9: C[256x32000] = A(bf16) @ W(f32)^T + bias  (+ LSE partials)
// GRAIN experiment at minimal bytes (r12 post-mortem): flat5/8 read W in
// 128B slices at 4KB stride (32k interleaved streams, ~14 GB/s/CU); here
// each W row's K-quarter is read as ONE contiguous 1KB instruction (8x
// coarser). K split in 4 quarters of 256; LDS 2 x [128 x pitch264] bf16
// (132 KB, 1 blk/CU — r10 proved >64KB static LDS works). 4 barriers total.
//   per quarter: WLOADQ(q+1) 8x1KB seq + ALOADQ(q+1) 8xuint4 (dbuf regs)
//                -> COMP 8 k-steps from LDS -> WSTOREQ(q+1) -> lgkm barrier.
// pitch 264 elems (528B): read banks (row*4+kq*4+j*16)%32 -> 8 groups x 8
// lanes = balanced minimum; write 4/bank balanced.
// MFMA 16x16x32_bf16; C/D: col=lane&15, row=(lane>>4)*4+reg (m89-verified).
// ===========================================================================
constexpr int QP = 264;              // LDS row pitch in bf16 elems
constexpr int GF_GRID = Vdim / 128;  // 250

__global__ __launch_bounds__(1024, 1)
void gemm_flat9(const unsigned short* __restrict__ A,
                const float* __restrict__ W,
                const float* __restrict__ bias,
                float* __restrict__ C,
                float2* __restrict__ plse)
{
  __shared__ unsigned short lWq[2][128 * QP];   // 2 x 66 KB = 132 KB

  const int t    = threadIdx.x;
  const int lane = t & 63;
  const int wv   = t >> 6;            // 0..15
  const int r16  = lane & 15;
  const int kq   = lane >> 4;         // 0..3
  const int n0   = blockIdx.x * 128;

  f32x4 acc[8];
#pragma unroll
  for (int n = 0; n < 8; ++n)
#pragma unroll
    for (int r = 0; r < 4; ++r) acc[n][r] = 0.f;

  f32x4 wr[8];                        // staged W rows (fp32 quarter slice)
  uint4 aA[8], aB[8];                 // A fragments, double-buffered sets

  // wave wv stages rows [wv*8, wv*8+8); one row-quarter = 1KB contiguous.
#define WLOADQ(Q) do {                                                         \
    _Pragma("unroll")                                                          \
    for (int j = 0; j < 8; ++j)                                                \
      wr[j] = *reinterpret_cast<const f32x4*>(                                 \
          W + (size_t)(n0 + wv * 8 + j) * 1024 + (Q) * 256 + lane * 4);        \
  } while (0)

#define WSTOREQ(BUF) do {                                                      \
    _Pragma("unroll")                                                          \
    for (int j = 0; j < 8; ++j) {                                              \
      ushort4 u_;                                                              \
      u_.x = f2bf(wr[j][0]); u_.y = f2bf(wr[j][1]);                            \
      u_.z = f2bf(wr[j][2]); u_.w = f2bf(wr[j][3]);                            \
      *reinterpret_cast<ushort4*>(                                             \
          &lWq[BUF][(wv * 8 + j) * QP + lane * 4]) = u_;                       \
    }                                                                          \
  } while (0)

#define ALOADQ(AR, Q) do {                                                     \
    _Pragma("unroll")                                                          \
    for (int j = 0; j < 8; ++j)                                                \
      AR[j] = *reinterpret_cast<const uint4*>(                                 \
          A + (size_t)(wv * 16 + r16) * 1024 + (Q) * 256 + j * 32 + kq * 8);   \
  } while (0)

#define COMPQ(AR, BUF) do {                                                    \
    _Pragma("unroll")                                                          \
    for (int j = 0; j < 8; ++j) {                                              \
      _Pragma("unroll")                                                        \
      for (int n = 0; n < 8; ++n) {                                            \
        bf16x8 bw_ = *reinterpret_cast<const bf16x8*>(                         \
            &lWq[BUF][(n * 16 + r16) * QP + j * 32 + kq * 8]);                 \
        acc[n] = __builtin_amdgcn_mfma_f32_16x16x32_bf16(                      \
            __builtin_bit_cast(bf16x8, AR[j]), bw_, acc[n], 0, 0, 0);          \
      }                                                                        \
    }                                                                          \
  } while (0)

#define GFBAR() do {                                                           \
    asm volatile("s_waitcnt lgkmcnt(0)" ::: "memory");                         \
    __builtin_amdgcn_sched_barrier(0);                                         \
    __builtin_amdgcn_s_barrier();                                              \
    __builtin_amdgcn_sched_barrier(0);                                         \
  } while (0)

  // prologue: quarter 0 staged to buf0; A(0) in flight
  WLOADQ(0);
  WSTOREQ(0);
  ALOADQ(aA, 0);
  GFBAR();

  // Q0: compute buf0/aA, stage q1 -> buf1
  WLOADQ(1); ALOADQ(aB, 1);
  COMPQ(aA, 0);
  WSTOREQ(1);
  GFBAR();

  // Q1: compute buf1/aB, stage q2 -> buf0
  WLOADQ(2); ALOADQ(aA, 2);
  COMPQ(aB, 1);
  WSTOREQ(0);
  GFBAR();

  // Q2: compute buf0/aA, stage q3 -> buf1
  WLOADQ(3); ALOADQ(aB, 3);
  COMPQ(aA, 0);
  WSTOREQ(1);
  GFBAR();

  // Q3: compute buf1/aB
  COMPQ(aB, 1);

#undef GFBAR
#undef COMPQ
#undef ALOADQ
#undef WSTOREQ
#undef WLOADQ

  // ---------------- epilogue: bias, store, LSE partials --------------------
#pragma unroll
  for (int n = 0; n < 8; ++n) {
    const int col = n0 + n * 16 + r16;
    const float bv = bias[col];
    const int rbase = wv * 16 + kq * 4;
#pragma unroll
    for (int r = 0; r < 4; ++r) {
      const float v = acc[n][r] + bv;
      acc[n][r] = v;
      C[(size_t)(rbase + r) * Vdim + col] = v;
    }
  }
#pragma unroll
  for (int r = 0; r < 4; ++r) {
    float mx = -1e30f;
#pragma unroll
    for (int n = 0; n < 8; ++n) mx = fmaxf(mx, acc[n][r]);
#pragma unroll
    for (int o = 1; o < 16; o <<= 1) mx = fmaxf(mx, __shfl_xor(mx, o, 16));
    float s = 0.f;
#pragma unroll
    for (int n = 0; n < 8; ++n) s += __expf(acc[n][r] - mx);
#pragma unroll
    for (int o = 1; o < 16; o <<= 1) s += __shfl_xor(s, o, 16);
    if (r16 == 0) {
      const int row = wv * 16 + kq * 4 + r;
      plse[(size_t)row * gridDim.x + blockIdx.x] = make_float2(mx, s);
    }
  }
}

// ===========================================================================
// gemm_multi: runtime-parameterized small-GEMM engine, TWO independent
// problems per dispatch (1D grid decode). Split-K atomicAdd, bias pre-init.
// BTRANS: W row-major [K x N] staged transposed. (r8 version, unchanged)
// ===========================================================================
struct GP {
  const float* A; const float* W; float* C;
  int K, ldc, ldb, col_off, aact, nsplit, gx;
};

template<bool BTRANS>
__global__ __launch_bounds__(256, 2)
void gemm_multi(GP q0, GP q1, int n0blk)
{
  constexpr int MT = 128, PITCH = 40, ITA = 4, MR = 2;

  __shared__ unsigned short lA[2 * MT * PITCH];
  __shared__ unsigned short lW[2 * 64 * PITCH];

  GP p = q0;
  int id = blockIdx.x;
  if (id >= n0blk) { p = q1; id -= n0blk; }
  const int bx  = id % p.gx;
  const int rem = id / p.gx;
  const int by  = rem & 1;
  const int kz  = rem >> 1;

  const int m0 = by * MT;
  const int n0 = bx * 64;
  const int NK = p.K / (32 * p.nsplit);
  const int kb = kz * NK;

  const int t  = threadIdx.x;
  const int tr = t >> 3;          // 0..31
  const int tc = (t & 7) * 4;

  const float* Af = p.A + (size_t)m0 * p.K;

  const int lane = t & 63;
  const int wv   = t >> 6;
  const int r16  = lane & 15;
  const int k8   = (lane >> 4) * 8;

  f32x4 acc[MR][4];
#pragma unroll
  for (int m = 0; m < MR; ++m)
#pragma unroll
    for (int n = 0; n < 4; ++n)
#pragma unroll
      for (int r = 0; r < 4; ++r) acc[m][n][r] = 0.f;

  struct RS { f32x4 ra[ITA]; f32x4 rw[2]; };

  auto loadT = [&](RS& rg, int kt) {
    const int ko = (kb + kt) * 32;
#pragma unroll
    for (int i = 0; i < ITA; ++i)
      rg.ra[i] = *reinterpret_cast<const f32x4*>(
          Af + (size_t)(tr + 32 * i) * p.K + ko + tc);
    if constexpr (BTRANS) {
      const float* wp = p.W + (size_t)(ko + tr) * p.ldb + n0 + (t & 7) * 8;
      rg.rw[0] = *reinterpret_cast<const f32x4*>(wp);
      rg.rw[1] = *reinterpret_cast<const f32x4*>(wp + 4);
    } else {
#pragma unroll
      for (int i = 0; i < 2; ++i)
        rg.rw[i] = *reinterpret_cast<const f32x4*>(
            p.W + (size_t)(n0 + tr + 32 * i) * p.ldb + ko + tc);
    }
  };

  auto storeT = [&](RS& rg, int bo) {
    unsigned short* sA = &lA[bo * MT * PITCH];
    unsigned short* sW = &lW[bo * 64 * PITCH];
#pragma unroll
    for (int i = 0; i < ITA; ++i) {
      f32x4 v = rg.ra[i];
      if (p.aact) { v[0]=fmaxf(v[0],0.f); v[1]=fmaxf(v[1],0.f);
                    v[2]=fmaxf(v[2],0.f); v[3]=fmaxf(v[3],0.f); }
      ushort4 u;
      u.x = f2bf(v[0]); u.y = f2bf(v[1]); u.z = f2bf(v[2]); u.w = f2bf(v[3]);
      *reinterpret_cast<ushort4*>(&sA[(tr + 32 * i) * PITCH + tc]) = u;
    }
    if constexpr (BTRANS) {
      const int hb = (t & 7) * 8;
#pragma unroll
      for (int j = 0; j < 4; ++j) {
        sW[(hb + j)     * PITCH + tr] = f2bf(rg.rw[0][j]);
        sW[(hb + 4 + j) * PITCH + tr] = f2bf(rg.rw[1][j]);
      }
    } else {
#pragma unroll
      for (int i = 0; i < 2; ++i) {
        f32x4 v = rg.rw[i]; ushort4 u;
        u.x = f2bf(v[0]); u.y = f2bf(v[1]); u.z = f2bf(v[2]); u.w = f2bf(v[3]);
        *reinterpret_cast<ushort4*>(&sW[(tr + 32 * i) * PITCH + tc]) = u;
      }
    }
  };

  auto comp = [&](int bo) {
    const unsigned short* sA = &lA[bo * MT * PITCH];
    const unsigned short* sW = &lW[bo * 64 * PITCH];
    bf16x8 af[MR], bfr[4];
#pragma unroll
    for (int m = 0; m < MR; ++m)
      af[m] = *reinterpret_cast<const bf16x8*>(&sA[(wv * 32 + m * 16 + r16) * PITCH + k8]);
#pragma unroll
    for (int n = 0; n < 4; ++n)
      bfr[n] = *reinterpret_cast<const bf16x8*>(&sW[(n * 16 + r16) * PITCH + k8]);
#pragma unroll
    for (int m = 0; m < MR; ++m)
#pragma unroll
      for (int n = 0; n < 4; ++n)
        acc[m][n] = __builtin_amdgcn_mfma_f32_16x16x32_bf16(af[m], bfr[n], acc[m][n], 0, 0, 0);
  };

#define GB_BARRIER() do { \
    asm volatile("s_waitcnt lgkmcnt(0)" ::: "memory"); \
    __builtin_amdgcn_sched_barrier(0); \
    __builtin_amdgcn_s_barrier(); \
  } while (0)

  RS ra_, rb_;
  loadT(ra_, 0);
  loadT(rb_, 1);
  storeT(ra_, 0);
  GB_BARRIER();

  for (int kt = 0; kt < NK; kt += 2) {
    if (kt + 2 < NK) loadT(ra_, kt + 2);
    comp(0);
    storeT(rb_, 1);
    GB_BARRIER();
    if (kt + 3 < NK) loadT(rb_, kt + 3);
    comp(1);
    if (kt + 2 < NK) {
      storeT(ra_, 0);
      GB_BARRIER();
    }
  }
#undef GB_BARRIER

#pragma unroll
  for (int n = 0; n < 4; ++n) {
    const int col = n0 + n * 16 + r16;
#pragma unroll
    for (int m = 0; m < MR; ++m) {
      const int rbase = m0 + wv * 32 + m * 16 + (lane >> 4) * 4;
#pragma unroll
      for (int r = 0; r < 4; ++r)
        atomicAdd(&p.C[(size_t)(rbase + r) * p.ldc + p.col_off + col],
                  acc[m][n][r]);
    }
  }
}

// ---- prep: X0=[emb|h], X1=[emb|0]; bias-init alog/xact/gi/gh ---------------
__global__ void prep_kernel(const int* __restrict__ ids, const float* __restrict__ hid,
                            const float* __restrict__ emb,
                            const float* __restrict__ attn_b, const float* __restrict__ comb_b,
                            const float* __restrict__ b_ih, const float* __restrict__ b_hh,
                            float* __restrict__ X0, float* __restrict__ X1,
                            float* __restrict__ alog, float* __restrict__ xact,
                            float* __restrict__ gi, float* __restrict__ gh)
{
  const int b = blockIdx.x, t = threadIdx.x;
  const int row = ids[b];
  f32x4 e = *reinterpret_cast<const f32x4*>(emb + (size_t)row * Hdim + t * 4);
  *reinterpret_cast<f32x4*>(X0 + (size_t)b * 2048 + t * 4) = e;
  *reinterpret_cast<f32x4*>(X1 + (size_t)b * 2048 + t * 4) = e;
  f32x4 h = *reinterpret_cast<const f32x4*>(hid + (size_t)b * Hdim + t * 4);
  *reinterpret_cast<f32x4*>(X0 + (size_t)b * 2048 + 1024 + t * 4) = h;
  f32x4 z4 = {0.f, 0.f, 0.f, 0.f};
  *reinterpret_cast<f32x4*>(X1 + (size_t)b * 2048 + 1024 + t * 4) = z4;
  if (t < 128)
    *reinterpret_cast<f32x4*>(alog + (size_t)b * Ldim + t * 4) =
        *reinterpret_cast<const f32x4*>(attn_b + t * 4);
  *reinterpret_cast<f32x4*>(xact + (size_t)b * Hdim + t * 4) =
      *reinterpret_cast<const f32x4*>(comb_b + t * 4);
#pragma unroll
  for (int i = 0; i < 3; ++i) {
    *reinterpret_cast<f32x4*>(gi + (size_t)b * 3072 + i * 1024 + t * 4) =
        *reinterpret_cast<const f32x4*>(b_ih + i * 1024 + t * 4);
    *reinterpret_cast<f32x4*>(gh + (size_t)b * 3072 + i * 1024 + t * 4) =
        *reinterpret_cast<const f32x4*>(b_hh + i * 1024 + t * 4);
  }
}

// ---- softmax over L=512 per row --------------------------------------------
__global__ void attn_softmax_kernel(const float* __restrict__ logits, float* __restrict__ wout)
{
  __shared__ float red[256];
  const int b = blockIdx.x, t = threadIdx.x;
  const float x0 = logits[b * Ldim + t];
  const float x1 = logits[b * Ldim + 256 + t];
  red[t] = fmaxf(x0, x1); __syncthreads();
  for (int o = 128; o > 0; o >>= 1) { if (t < o) red[t] = fmaxf(red[t], red[t + o]); __syncthreads(); }
  const float m = red[0]; __syncthreads();
  const float e0 = __expf(x0 - m), e1 = __expf(x1 - m);
  red[t] = e0 + e1; __syncthreads();
  for (int o = 128; o > 0; o >>= 1) { if (t < o) red[t] += red[t + o]; __syncthreads(); }
  const float inv = 1.f / red[0];
  wout[b * Ldim + t]       = e0 * inv;
  wout[b * Ldim + 256 + t] = e1 * inv;
}

// ---- GRU pointwise ---------------------------------------------------------
DEVI float sigm(float x) { return 1.f / (1.f + __expf(-x)); }

__global__ void gru_kernel(const float* __restrict__ gi, const float* __restrict__ gh,
                           const float* __restrict__ hin,
                           float* __restrict__ hnew, unsigned short* __restrict__ hnbf)
{
  const int idx = blockIdx.x * 256 + threadIdx.x;
  const int b = idx >> 10, j = idx & 1023;
  const float* gib = gi + (size_t)b * 3072;
  const float* ghb = gh + (size_t)b * 3072;
  const float r = sigm(gib[j] + ghb[j]);
  const float z = sigm(gib[1024 + j] + ghb[1024 + j]);
  const float n = tanhf(gib[2048 + j] + r * ghb[2048 + j]);
  const float h = hin[idx];
  const float hn = (1.f - z) * n + z * h;
  hnew[idx] = hn;
  hnbf[idx] = f2bf(hn);
}

// ---- fused: per-block LSE recompute + subtract slice in place --------------
__global__ void lsm_sub2(const float2* __restrict__ part, int npart,
                         float* __restrict__ out)
{
  __shared__ float rm[256], rs[256];
  const int b = blockIdx.x >> 3, c = blockIdx.x & 7;
  const int t = threadIdx.x;
  float m = -1e30f, s = 0.f;
  for (int j = t; j < npart; j += 256) {
    const float2 p = part[(size_t)b * npart + j];
    const float nm = fmaxf(m, p.x);
    s = s * __expf(m - nm) + p.y * __expf(p.x - nm);
    m = nm;
  }
  rm[t] = m; rs[t] = s; __syncthreads();
  for (int o = 128; o > 0; o >>= 1) {
    if (t < o) {
      const float m2 = rm[t + o], s2 = rs[t + o];
      const float nm = fmaxf(rm[t], m2);
      rs[t] = rs[t] * __expf(rm[t] - nm) + s2 * __expf(m2 - nm);
      rm[t] = nm;
    }
    __syncthreads();
  }
  const float lse = rm[0] + __logf(rs[0]);
  f32x4* row4 = reinterpret_cast<f32x4*>(out + (size_t)b * Vdim) + c * 1000;
  for (int i = t; i < 1000; i += 256) {
    f32x4 x = row4[i];
    x[0] -= lse; x[1] -= lse; x[2] -= lse; x[3] -= lse;
    row4[i] = x;
  }
}

// ---------------------------------------------------------------------------
extern "C" void kernel_launch(void* const* d_in, const int* in_sizes, int n_in,
                              void* d_out, int out_size, void* d_ws, size_t ws_size,
                              hipStream_t stream)
{
  (void)in_sizes; (void)n_in; (void)out_size; (void)ws_size;

  const int*   ids    = (const int*)  d_in[0];
  const float* hid    = (const float*)d_in[1];
  const float* enc    = (const float*)d_in[2];
  const float* emb    = (const float*)d_in[3];
  const float* attn_W = (const float*)d_in[4];
  const float* attn_b = (const float*)d_in[5];
  const float* comb_W = (const float*)d_in[6];
  const float* comb_b = (const float*)d_in[7];
  const float* W_ih   = (const float*)d_in[8];
  const float* W_hh   = (const float*)d_in[9];
  const float* b_ih   = (const float*)d_in[10];
  const float* b_hh   = (const float*)d_in[11];
  const float* out_W  = (const float*)d_in[12];
  const float* out_b  = (const float*)d_in[13];

  float* out_logits = (float*)d_out;                       // [B,V]
  float* out_h      = out_logits + (size_t)Bdim * Vdim;    // [B,H]
  float* out_attw   = out_h + (size_t)Bdim * Hdim;         // [B,L]

  char* w = (char*)d_ws;
  float* X0   = (float*)w; w += (size_t)Bdim * 2048 * 4;
  float* X1   = (float*)w; w += (size_t)Bdim * 2048 * 4;
  float* alog = (float*)w; w += (size_t)Bdim * Ldim * 4;
  float* xact = (float*)w; w += (size_t)Bdim * Hdim * 4;
  float* gi   = (float*)w; w += (size_t)Bdim * 3 * Hdim * 4;
  float* gh   = (float*)w; w += (size_t)Bdim * 3 * Hdim * 4;
  unsigned short* hnbf = (unsigned short*)w; w += (size_t)Bdim * Hdim * 2;
  float2* plse = (float2*)w; w += (size_t)Bdim * GF_GRID * 8;

  prep_kernel<<<Bdim, 256, 0, stream>>>(ids, hid, emb, attn_b, comb_b, b_ih, b_hh,
                                        X0, X1, alog, xact, gi, gh);

  // D1: attn logits [B,L] += X0 @ attn_W^T  AND  gh += h @ W_hh^T (independent)
  {
    GP p0 = { X0,  attn_W, alog, 2048, Ldim,     2048, 0, 0, 8,  Ldim / 64 };
    GP p1 = { hid, W_hh,   gh,   1024, 3 * Hdim, 1024, 0, 0, 4,  3 * Hdim / 64 };
    const int n0blk = p0.gx * 2 * p0.nsplit;                 // 128
    const int nblk  = n0blk + p1.gx * 2 * p1.nsplit;         // 128 + 384
    gemm_multi<false><<<nblk, 256, 0, stream>>>(p0, p1, n0blk);
  }

  attn_softmax_kernel<<<Bdim, 256, 0, stream>>>(alog, out_attw);

  // D2: attn_applied -> X1 right half: attn_w @ enc (enc transposed on stage)
  {
    GP p0 = { out_attw, enc, X1, 512, 2048, Hdim, 1024, 0, 4, Hdim / 64 };
    const int nblk = p0.gx * 2 * p0.nsplit;                  // 128
    gemm_multi<true><<<nblk, 256, 0, stream>>>(p0, p0, nblk);
  }

  // D3: xact += X1 @ comb_W^T   (ReLU deferred to D4's A-staging)
  {
    GP p0 = { X1, comb_W, xact, 2048, Hdim, 2048, 0, 0, 8, Hdim / 64 };
    const int nblk = p0.gx * 2 * p0.nsplit;                  // 256
    gemm_multi<false><<<nblk, 256, 0, stream>>>(p0, p0, nblk);
  }

  // D4: gi += relu(xact) @ W_ih^T
  {
    GP p0 = { xact, W_ih, gi, 1024, 3 * Hdim, 1024, 0, 1, 4, 3 * Hdim / 64 };
    const int nblk = p0.gx * 2 * p0.nsplit;                  // 384
    gemm_multi<false><<<nblk, 256, 0, stream>>>(p0, p0, nblk);
  }

  gru_kernel<<<Bdim * Hdim / 256, 256, 0, stream>>>(gi, gh, hid, out_h, hnbf);

  // logits [B,V] = h_new @ out_W^T + out_b  (K-quartered burst-grain GEMM)
  gemm_flat9<<<GF_GRID, 1024, 0, stream>>>(hnbf, out_W, out_b, out_logits, plse);

  // fused LSE recompute + in-place subtract
  lsm_sub2<<<Bdim * 8, 256, 0, stream>>>(plse, GF_GRID, out_logits);
}

// Round 14
// 115.809 us; speedup vs baseline: 1.1644x; 1.1644x over previous
//
#include <hip/hip_runtime.h>
#include <hip/hip_bf16.h>
#include <cstdint>

#define DEVI __device__ __forceinline__

typedef __bf16 bf16x8 __attribute__((ext_vector_type(8)));
typedef float  f32x4  __attribute__((ext_vector_type(4)));

constexpr int Hdim = 1024;
constexpr int Vdim = 32000;
constexpr int Ldim = 512;
constexpr int Bdim = 256;

DEVI unsigned short f2bf(float f) {
  __bf16 h = (__bf16)f;                       // RNE
  return __builtin_bit_cast(unsigned short, h);
}

// ===========================================================================
// gemm_flat5 (FROZEN — best measured): C[256x32000]=A(bf16)@W(f32)^T + bias.
// ~75us. Exhaustive falsification sweep (r2-r13): schedule variants, burst
// grain (2x), occupancy, pipeline depth, grid-sync fusion, producer-consumer
// all land 75-190us; this structure is the floor for this decomposition.
// Ntile 128, grid 250, depth-2 reg rotation, 4 LDS bufs, W read once.
// MFMA 16x16x32_bf16; C/D: col=lane&15, row=(lane>>4)*4+reg (m89-verified).
// ===========================================================================
constexpr int FP4 = 36;              // LDS row pitch in bf16 elems
constexpr int GF_GRID = Vdim / 128;  // 250

__global__ __launch_bounds__(1024, 4)
void gemm_flat5(const unsigned short* __restrict__ A,
                const float* __restrict__ W,
                const float* __restrict__ bias,
                float* __restrict__ C,
                float2* __restrict__ plse)
{
  __shared__ unsigned short lW[4][128 * FP4];   // 4 x 9216 B = 36 KB

  const int t    = threadIdx.x;
  const int lane = t & 63;
  const int wv   = t >> 6;            // 0..15 -> M rows [wv*16, wv*16+16)
  const int r16  = lane & 15;
  const int k8   = (lane >> 4) * 8;
  const int n0   = blockIdx.x * 128;

  const int srow = t >> 3;            // staging row 0..127
  const int stc  = (t & 7) * 4;       // staging k-elem

  const float*          Wb = W + (size_t)(n0 + srow) * 1024 + stc;
  const unsigned short* Ab = A + (size_t)(wv * 16 + r16) * 1024 + k8;

  f32x4 acc[8];
#pragma unroll
  for (int n = 0; n < 8; ++n)
#pragma unroll
    for (int r = 0; r < 4; ++r) acc[n][r] = 0.f;

  f32x4 w0_, w1_;
  uint4 a0_, a1_, a2_, a3_;

#define LOADW(RW, KT) RW = *reinterpret_cast<const f32x4*>(Wb + (KT) * 32)
#define LOADA(RA, KT) RA = *reinterpret_cast<const uint4*>(Ab + (KT) * 32)

#define STOREW(RW, BUF) do {                                                   \
    ushort4 u_;                                                                \
    u_.x = f2bf(RW[0]); u_.y = f2bf(RW[1]);                                    \
    u_.z = f2bf(RW[2]); u_.w = f2bf(RW[3]);                                    \
    *reinterpret_cast<ushort4*>(&lW[BUF][srow * FP4 + stc]) = u_;              \
  } while (0)

#define COMP(RA, BUF) do {                                                     \
    _Pragma("unroll")                                                          \
    for (int n = 0; n < 8; ++n) {                                              \
      bf16x8 bw_ = *reinterpret_cast<const bf16x8*>(                           \
          &lW[BUF][(n * 16 + r16) * FP4 + k8]);                                \
      acc[n] = __builtin_amdgcn_mfma_f32_16x16x32_bf16(                        \
          __builtin_bit_cast(bf16x8, RA), bw_, acc[n], 0, 0, 0);               \
    }                                                                          \
  } while (0)

  LOADW(w0_, 0); LOADW(w1_, 1);
  LOADA(a0_, 0); LOADA(a1_, 1); LOADA(a2_, 2); LOADA(a3_, 3);
  STOREW(w0_, 0); LOADW(w0_, 2);
  STOREW(w1_, 1); LOADW(w1_, 3);
  __syncthreads();

  for (int kt = 0; kt < 32; kt += 4) {
    COMP(a0_, 0);
    STOREW(w0_, 2);
    { const int kn = (kt + 4 < 32) ? kt + 4 : 31; LOADW(w0_, kn); LOADA(a0_, kn); }
    __syncthreads();

    COMP(a1_, 1);
    STOREW(w1_, 3);
    { const int kn = (kt + 5 < 32) ? kt + 5 : 31; LOADW(w1_, kn); LOADA(a1_, kn); }
    __syncthreads();

    COMP(a2_, 2);
    STOREW(w0_, 0);
    { const int kn = (kt + 6 < 32) ? kt + 6 : 31; LOADW(w0_, kn); LOADA(a2_, kn); }
    __syncthreads();

    COMP(a3_, 3);
    STOREW(w1_, 1);
    { const int kn = (kt + 7 < 32) ? kt + 7 : 31; LOADW(w1_, kn); LOADA(a3_, kn); }
    __syncthreads();
  }

#undef COMP
#undef STOREW
#undef LOADA
#undef LOADW

#pragma unroll
  for (int n = 0; n < 8; ++n) {
    const int col = n0 + n * 16 + r16;
    const float bv = bias[col];
    const int rbase = wv * 16 + (lane >> 4) * 4;
#pragma unroll
    for (int r = 0; r < 4; ++r) {
      const float v = acc[n][r] + bv;
      acc[n][r] = v;
      C[(size_t)(rbase + r) * Vdim + col] = v;
    }
  }
#pragma unroll
  for (int r = 0; r < 4; ++r) {
    float mx = -1e30f;
#pragma unroll
    for (int n = 0; n < 8; ++n) mx = fmaxf(mx, acc[n][r]);
#pragma unroll
    for (int o = 1; o < 16; o <<= 1) mx = fmaxf(mx, __shfl_xor(mx, o, 16));
    float s = 0.f;
#pragma unroll
    for (int n = 0; n < 8; ++n) s += __expf(acc[n][r] - mx);
#pragma unroll
    for (int o = 1; o < 16; o <<= 1) s += __shfl_xor(s, o, 16);
    if (r16 == 0) {
      const int row = wv * 16 + (lane >> 4) * 4 + r;
      plse[(size_t)row * gridDim.x + blockIdx.x] = make_float2(mx, s);
    }
  }
}

// ===========================================================================
// gemm_multi: runtime-parameterized small-GEMM engine, TWO independent
// problems per dispatch (1D grid decode). Split-K atomicAdd, bias pre-init.
// BTRANS: W row-major [K x N] staged transposed.
// ===========================================================================
struct GP {
  const float* A; const float* W; float* C;
  int K, ldc, ldb, col_off, aact, nsplit, gx;
};

template<bool BTRANS>
__global__ __launch_bounds__(256, 2)
void gemm_multi(GP q0, GP q1, int n0blk)
{
  constexpr int MT = 128, PITCH = 40, ITA = 4, MR = 2;

  __shared__ unsigned short lA[2 * MT * PITCH];
  __shared__ unsigned short lW[2 * 64 * PITCH];

  GP p = q0;
  int id = blockIdx.x;
  if (id >= n0blk) { p = q1; id -= n0blk; }
  const int bx  = id % p.gx;
  const int rem = id / p.gx;
  const int by  = rem & 1;
  const int kz  = rem >> 1;

  const int m0 = by * MT;
  const int n0 = bx * 64;
  const int NK = p.K / (32 * p.nsplit);
  const int kb = kz * NK;

  const int t  = threadIdx.x;
  const int tr = t >> 3;          // 0..31
  const int tc = (t & 7) * 4;

  const float* Af = p.A + (size_t)m0 * p.K;

  const int lane = t & 63;
  const int wv   = t >> 6;
  const int r16  = lane & 15;
  const int k8   = (lane >> 4) * 8;

  f32x4 acc[MR][4];
#pragma unroll
  for (int m = 0; m < MR; ++m)
#pragma unroll
    for (int n = 0; n < 4; ++n)
#pragma unroll
      for (int r = 0; r < 4; ++r) acc[m][n][r] = 0.f;

  struct RS { f32x4 ra[ITA]; f32x4 rw[2]; };

  auto loadT = [&](RS& rg, int kt) {
    const int ko = (kb + kt) * 32;
#pragma unroll
    for (int i = 0; i < ITA; ++i)
      rg.ra[i] = *reinterpret_cast<const f32x4*>(
          Af + (size_t)(tr + 32 * i) * p.K + ko + tc);
    if constexpr (BTRANS) {
      const float* wp = p.W + (size_t)(ko + tr) * p.ldb + n0 + (t & 7) * 8;
      rg.rw[0] = *reinterpret_cast<const f32x4*>(wp);
      rg.rw[1] = *reinterpret_cast<const f32x4*>(wp + 4);
    } else {
#pragma unroll
      for (int i = 0; i < 2; ++i)
        rg.rw[i] = *reinterpret_cast<const f32x4*>(
            p.W + (size_t)(n0 + tr + 32 * i) * p.ldb + ko + tc);
    }
  };

  auto storeT = [&](RS& rg, int bo) {
    unsigned short* sA = &lA[bo * MT * PITCH];
    unsigned short* sW = &lW[bo * 64 * PITCH];
#pragma unroll
    for (int i = 0; i < ITA; ++i) {
      f32x4 v = rg.ra[i];
      if (p.aact) { v[0]=fmaxf(v[0],0.f); v[1]=fmaxf(v[1],0.f);
                    v[2]=fmaxf(v[2],0.f); v[3]=fmaxf(v[3],0.f); }
      ushort4 u;
      u.x = f2bf(v[0]); u.y = f2bf(v[1]); u.z = f2bf(v[2]); u.w = f2bf(v[3]);
      *reinterpret_cast<ushort4*>(&sA[(tr + 32 * i) * PITCH + tc]) = u;
    }
    if constexpr (BTRANS) {
      const int hb = (t & 7) * 8;
#pragma unroll
      for (int j = 0; j < 4; ++j) {
        sW[(hb + j)     * PITCH + tr] = f2bf(rg.rw[0][j]);
        sW[(hb + 4 + j) * PITCH + tr] = f2bf(rg.rw[1][j]);
      }
    } else {
#pragma unroll
      for (int i = 0; i < 2; ++i) {
        f32x4 v = rg.rw[i]; ushort4 u;
        u.x = f2bf(v[0]); u.y = f2bf(v[1]); u.z = f2bf(v[2]); u.w = f2bf(v[3]);
        *reinterpret_cast<ushort4*>(&sW[(tr + 32 * i) * PITCH + tc]) = u;
      }
    }
  };

  auto comp = [&](int bo) {
    const unsigned short* sA = &lA[bo * MT * PITCH];
    const unsigned short* sW = &lW[bo * 64 * PITCH];
    bf16x8 af[MR], bfr[4];
#pragma unroll
    for (int m = 0; m < MR; ++m)
      af[m] = *reinterpret_cast<const bf16x8*>(&sA[(wv * 32 + m * 16 + r16) * PITCH + k8]);
#pragma unroll
    for (int n = 0; n < 4; ++n)
      bfr[n] = *reinterpret_cast<const bf16x8*>(&sW[(n * 16 + r16) * PITCH + k8]);
#pragma unroll
    for (int m = 0; m < MR; ++m)
#pragma unroll
      for (int n = 0; n < 4; ++n)
        acc[m][n] = __builtin_amdgcn_mfma_f32_16x16x32_bf16(af[m], bfr[n], acc[m][n], 0, 0, 0);
  };

#define GB_BARRIER() do { \
    asm volatile("s_waitcnt lgkmcnt(0)" ::: "memory"); \
    __builtin_amdgcn_sched_barrier(0); \
    __builtin_amdgcn_s_barrier(); \
  } while (0)

  RS ra_, rb_;
  loadT(ra_, 0);
  loadT(rb_, 1);
  storeT(ra_, 0);
  GB_BARRIER();

  for (int kt = 0; kt < NK; kt += 2) {
    if (kt + 2 < NK) loadT(ra_, kt + 2);
    comp(0);
    storeT(rb_, 1);
    GB_BARRIER();
    if (kt + 3 < NK) loadT(rb_, kt + 3);
    comp(1);
    if (kt + 2 < NK) {
      storeT(ra_, 0);
      GB_BARRIER();
    }
  }
#undef GB_BARRIER

#pragma unroll
  for (int n = 0; n < 4; ++n) {
    const int col = n0 + n * 16 + r16;
#pragma unroll
    for (int m = 0; m < MR; ++m) {
      const int rbase = m0 + wv * 32 + m * 16 + (lane >> 4) * 4;
#pragma unroll
      for (int r = 0; r < 4; ++r)
        atomicAdd(&p.C[(size_t)(rbase + r) * p.ldc + p.col_off + col],
                  acc[m][n][r]);
    }
  }
}

// ---- prep: X0=[emb|h], X1=[emb|0]; bias-init alog/xact/gi/gh ---------------
__global__ void prep_kernel(const int* __restrict__ ids, const float* __restrict__ hid,
                            const float* __restrict__ emb,
                            const float* __restrict__ attn_b, const float* __restrict__ comb_b,
                            const float* __restrict__ b_ih, const float* __restrict__ b_hh,
                            float* __restrict__ X0, float* __restrict__ X1,
                            float* __restrict__ alog, float* __restrict__ xact,
                            float* __restrict__ gi, float* __restrict__ gh)
{
  const int b = blockIdx.x, t = threadIdx.x;
  const int row = ids[b];
  f32x4 e = *reinterpret_cast<const f32x4*>(emb + (size_t)row * Hdim + t * 4);
  *reinterpret_cast<f32x4*>(X0 + (size_t)b * 2048 + t * 4) = e;
  *reinterpret_cast<f32x4*>(X1 + (size_t)b * 2048 + t * 4) = e;
  f32x4 h = *reinterpret_cast<const f32x4*>(hid + (size_t)b * Hdim + t * 4);
  *reinterpret_cast<f32x4*>(X0 + (size_t)b * 2048 + 1024 + t * 4) = h;
  f32x4 z4 = {0.f, 0.f, 0.f, 0.f};
  *reinterpret_cast<f32x4*>(X1 + (size_t)b * 2048 + 1024 + t * 4) = z4;
  if (t < 128)
    *reinterpret_cast<f32x4*>(alog + (size_t)b * Ldim + t * 4) =
        *reinterpret_cast<const f32x4*>(attn_b + t * 4);
  *reinterpret_cast<f32x4*>(xact + (size_t)b * Hdim + t * 4) =
      *reinterpret_cast<const f32x4*>(comb_b + t * 4);
#pragma unroll
  for (int i = 0; i < 3; ++i) {
    *reinterpret_cast<f32x4*>(gi + (size_t)b * 3072 + i * 1024 + t * 4) =
        *reinterpret_cast<const f32x4*>(b_ih + i * 1024 + t * 4);
    *reinterpret_cast<f32x4*>(gh + (size_t)b * 3072 + i * 1024 + t * 4) =
        *reinterpret_cast<const f32x4*>(b_hh + i * 1024 + t * 4);
  }
}

// ---- softmax over L=512 per row --------------------------------------------
__global__ void attn_softmax_kernel(const float* __restrict__ logits, float* __restrict__ wout)
{
  __shared__ float red[256];
  const int b = blockIdx.x, t = threadIdx.x;
  const float x0 = logits[b * Ldim + t];
  const float x1 = logits[b * Ldim + 256 + t];
  red[t] = fmaxf(x0, x1); __syncthreads();
  for (int o = 128; o > 0; o >>= 1) { if (t < o) red[t] = fmaxf(red[t], red[t + o]); __syncthreads(); }
  const float m = red[0]; __syncthreads();
  const float e0 = __expf(x0 - m), e1 = __expf(x1 - m);
  red[t] = e0 + e1; __syncthreads();
  for (int o = 128; o > 0; o >>= 1) { if (t < o) red[t] += red[t + o]; __syncthreads(); }
  const float inv = 1.f / red[0];
  wout[b * Ldim + t]       = e0 * inv;
  wout[b * Ldim + 256 + t] = e1 * inv;
}

// ---- GRU pointwise ---------------------------------------------------------
DEVI float sigm(float x) { return 1.f / (1.f + __expf(-x)); }

__global__ void gru_kernel(const float* __restrict__ gi, const float* __restrict__ gh,
                           const float* __restrict__ hin,
                           float* __restrict__ hnew, unsigned short* __restrict__ hnbf)
{
  const int idx = blockIdx.x * 256 + threadIdx.x;
  const int b = idx >> 10, j = idx & 1023;
  const float* gib = gi + (size_t)b * 3072;
  const float* ghb = gh + (size_t)b * 3072;
  const float r = sigm(gib[j] + ghb[j]);
  const float z = sigm(gib[1024 + j] + ghb[1024 + j]);
  const float n = tanhf(gib[2048 + j] + r * ghb[2048 + j]);
  const float h = hin[idx];
  const float hn = (1.f - z) * n + z * h;
  hnew[idx] = hn;
  hnbf[idx] = f2bf(hn);
}

// ---- fused: per-block LSE recompute + subtract slice in place --------------
__global__ void lsm_sub2(const float2* __restrict__ part, int npart,
                         float* __restrict__ out)
{
  __shared__ float rm[256], rs[256];
  const int b = blockIdx.x >> 3, c = blockIdx.x & 7;
  const int t = threadIdx.x;
  float m = -1e30f, s = 0.f;
  for (int j = t; j < npart; j += 256) {
    const float2 p = part[(size_t)b * npart + j];
    const float nm = fmaxf(m, p.x);
    s = s * __expf(m - nm) + p.y * __expf(p.x - nm);
    m = nm;
  }
  rm[t] = m; rs[t] = s; __syncthreads();
  for (int o = 128; o > 0; o >>= 1) {
    if (t < o) {
      const float m2 = rm[t + o], s2 = rs[t + o];
      const float nm = fmaxf(rm[t], m2);
      rs[t] = rs[t] * __expf(rm[t] - nm) + s2 * __expf(m2 - nm);
      rm[t] = nm;
    }
    __syncthreads();
  }
  const float lse = rm[0] + __logf(rs[0]);
  f32x4* row4 = reinterpret_cast<f32x4*>(out + (size_t)b * Vdim) + c * 1000;
  for (int i = t; i < 1000; i += 256) {
    f32x4 x = row4[i];
    x[0] -= lse; x[1] -= lse; x[2] -= lse; x[3] -= lse;
    row4[i] = x;
  }
}

// ---------------------------------------------------------------------------
extern "C" void kernel_launch(void* const* d_in, const int* in_sizes, int n_in,
                              void* d_out, int out_size, void* d_ws, size_t ws_size,
                              hipStream_t stream)
{
  (void)in_sizes; (void)n_in; (void)out_size; (void)ws_size;

  const int*   ids    = (const int*)  d_in[0];
  const float* hid    = (const float*)d_in[1];
  const float* enc    = (const float*)d_in[2];
  const float* emb    = (const float*)d_in[3];
  const float* attn_W = (const float*)d_in[4];
  const float* attn_b = (const float*)d_in[5];
  const float* comb_W = (const float*)d_in[6];
  const float* comb_b = (const float*)d_in[7];
  const float* W_ih   = (const float*)d_in[8];
  const float* W_hh   = (const float*)d_in[9];
  const float* b_ih   = (const float*)d_in[10];
  const float* b_hh   = (const float*)d_in[11];
  const float* out_W  = (const float*)d_in[12];
  const float* out_b  = (const float*)d_in[13];

  float* out_logits = (float*)d_out;                       // [B,V]
  float* out_h      = out_logits + (size_t)Bdim * Vdim;    // [B,H]
  float* out_attw   = out_h + (size_t)Bdim * Hdim;         // [B,L]

  char* w = (char*)d_ws;
  float* X0   = (float*)w; w += (size_t)Bdim * 2048 * 4;
  float* X1   = (float*)w; w += (size_t)Bdim * 2048 * 4;
  float* alog = (float*)w; w += (size_t)Bdim * Ldim * 4;
  float* xact = (float*)w; w += (size_t)Bdim * Hdim * 4;
  float* gi   = (float*)w; w += (size_t)Bdim * 3 * Hdim * 4;
  float* gh   = (float*)w; w += (size_t)Bdim * 3 * Hdim * 4;
  unsigned short* hnbf = (unsigned short*)w; w += (size_t)Bdim * Hdim * 2;
  float2* plse = (float2*)w; w += (size_t)Bdim * GF_GRID * 8;

  prep_kernel<<<Bdim, 256, 0, stream>>>(ids, hid, emb, attn_b, comb_b, b_ih, b_hh,
                                        X0, X1, alog, xact, gi, gh);

  // D1: attn logits [B,L] += X0 @ attn_W^T  AND  gh += h @ W_hh^T (independent)
  {
    GP p0 = { X0,  attn_W, alog, 2048, Ldim,     2048, 0, 0, 8,  Ldim / 64 };
    GP p1 = { hid, W_hh,   gh,   1024, 3 * Hdim, 1024, 0, 0, 4,  3 * Hdim / 64 };
    const int n0blk = p0.gx * 2 * p0.nsplit;                 // 128
    const int nblk  = n0blk + p1.gx * 2 * p1.nsplit;         // 128 + 384
    gemm_multi<false><<<nblk, 256, 0, stream>>>(p0, p1, n0blk);
  }

  attn_softmax_kernel<<<Bdim, 256, 0, stream>>>(alog, out_attw);

  // D2: attn_applied -> X1 right half: attn_w @ enc (enc transposed on stage)
  {
    GP p0 = { out_attw, enc, X1, 512, 2048, Hdim, 1024, 0, 4, Hdim / 64 };
    const int nblk = p0.gx * 2 * p0.nsplit;                  // 128
    gemm_multi<true><<<nblk, 256, 0, stream>>>(p0, p0, nblk);
  }

  // D3: xact += X1 @ comb_W^T   (ReLU deferred to D4's A-staging)
  {
    GP p0 = { X1, comb_W, xact, 2048, Hdim, 2048, 0, 0, 8, Hdim / 64 };
    const int nblk = p0.gx * 2 * p0.nsplit;                  // 256
    gemm_multi<false><<<nblk, 256, 0, stream>>>(p0, p0, nblk);
  }

  // D4: gi += relu(xact) @ W_ih^T
  {
    GP p0 = { xact, W_ih, gi, 1024, 3 * Hdim, 1024, 0, 1, 4, 3 * Hdim / 64 };
    const int nblk = p0.gx * 2 * p0.nsplit;                  // 384
    gemm_multi<false><<<nblk, 256, 0, stream>>>(p0, p0, nblk);
  }

  gru_kernel<<<Bdim * Hdim / 256, 256, 0, stream>>>(gi, gh, hid, out_h, hnbf);

  // logits [B,V] = h_new @ out_W^T + out_b  (frozen flat5)
  gemm_flat5<<<GF_GRID, 1024, 0, stream>>>(hnbf, out_W, out_b, out_logits, plse);

  // fused LSE recompute + in-place subtract
  lsm_sub2<<<Bdim * 8, 256, 0, stream>>>(plse, GF_GRID, out_logits);
}